// Round 26
// baseline (462.359 us; speedup 1.0000x reference)
//
#include <hip/hip_runtime.h>

// Problem constants (match reference setup_inputs)
#define NODES 50000
#define NEDGE 1600000
#define ND 64      // NODE_DIM
#define ED 32      // EDGE_DIM
#define HID 64     // HIDDEN
#define IN_DIM 96  // ND + ED

#define TW 16        // edges per wave-private micro-tile
#define H_LD   72    // bf16/row: 64+8 pad -> 144 B rows (h tile)
#define MT_LD  24    // mT row stride (bf16): 48 B rows, b128-aligned, low-conflict
#define W1_LD  104   // w1T row stride (bf16)
#define W2_LD  72    // w2T row stride (bf16)
#define SC_ELEM 1536 // per-wave scratch: max(16*H_LD=1152, 64*MT_LD=1536) bf16

typedef __bf16 bf16_t;
typedef __bf16 bf16x4_t __attribute__((ext_vector_type(4)));
typedef __bf16 bf16x8_t __attribute__((ext_vector_type(8)));
typedef float  f32x4_t  __attribute__((ext_vector_type(4)));
typedef unsigned int u32;

#define SCAN_B 256
#define SCAN_NBLK ((NODES + SCAN_B - 1) / SCAN_B)   // 196

#define NXCD 8
#define NODES_PER_G ((NODES + NXCD - 1) / NXCD)   // 6250

// ---------------- K0: zero cnt only (must precede hist's atomics) ----------------
__global__ void zero_cnt_kernel(int* __restrict__ cnt) {
    int i = blockIdx.x * blockDim.x + threadIdx.x;
    int stride = gridDim.x * blockDim.x;
    for (int idx = i; idx < NODES; idx += stride) cnt[idx] = 0;
}

// ---------------- K1: fused out-zero + histogram + packed (dst<<16)|rank ----------------
__global__ void hist_kernel(const int* __restrict__ ei, int* __restrict__ cnt,
                            u32* __restrict__ pk, float* __restrict__ out) {
    int i = blockIdx.x * blockDim.x + threadIdx.x;
    int stride = gridDim.x * blockDim.x;
    {
        float4 z = {0.0f, 0.0f, 0.0f, 0.0f};
        for (int idx = i; idx < NODES * ND / 4; idx += stride) ((float4*)out)[idx] = z;
    }
    for (int e = i; e < NEDGE; e += stride) {
        int d = ei[NEDGE + e];
        int r = atomicAdd(&cnt[d], 1);
        pk[e] = ((u32)d << 16) | (u32)r;
    }
}

// ---------------- K2a: per-block partial sums of cnt ----------------
__global__ void scan_sum_kernel(const int* __restrict__ cnt, int* __restrict__ bsum) {
    __shared__ int sh[SCAN_B];
    const int t = threadIdx.x, b = blockIdx.x;
    const int i = b * SCAN_B + t;
    sh[t] = (i < NODES) ? cnt[i] : 0;
    __syncthreads();
    for (int d = SCAN_B / 2; d > 0; d >>= 1) {
        if (t < d) sh[t] += sh[t + d];
        __syncthreads();
    }
    if (t == 0) bsum[b] = sh[0];
}

// ---------------- K2b: fill cursor (top-scan of bsum computed redundantly per block) ----------------
__global__ void scan_fill_kernel(const int* __restrict__ cnt, const int* __restrict__ bsum,
                                 int* __restrict__ cursor) {
    __shared__ int sh[SCAN_B];
    const int t = threadIdx.x, b = blockIdx.x;
    sh[t] = (t < SCAN_NBLK) ? bsum[t] : 0;
    __syncthreads();
    for (int d = 1; d < SCAN_B; d <<= 1) {
        int v = (t >= d) ? sh[t - d] : 0;
        __syncthreads();
        sh[t] += v;
        __syncthreads();
    }
    const int base = (b == 0) ? 0 : sh[b - 1];
    __syncthreads();
    const int i = b * SCAN_B + t;
    int v = (i < NODES) ? cnt[i] : 0;
    sh[t] = v;
    __syncthreads();
    for (int d = 1; d < SCAN_B; d <<= 1) {
        int u = (t >= d) ? sh[t - d] : 0;
        __syncthreads();
        sh[t] += u;
        __syncthreads();
    }
    if (i < NODES) cursor[i] = base + sh[t] - v;   // exclusive
}

// ---------------- K3: bucket-scatter, XCD-partitioned, NO atomics, single stream ----------------
__global__ void bucket_kernel(const u32* __restrict__ pk, const int* __restrict__ cursor,
                              int2* __restrict__ pd) {
    const int g   = blockIdx.x & (NXCD - 1);
    const int bg  = blockIdx.x >> 3;
    const int bpg = gridDim.x >> 3;
    const int lo  = g * NODES_PER_G;
    const int hi  = min(lo + NODES_PER_G, NODES);
    int i = bg * blockDim.x + threadIdx.x;
    int stride = bpg * blockDim.x;
    for (int e = i; e < NEDGE; e += stride) {
        u32 p = pk[e];
        int d = (int)(p >> 16);
        if (d >= lo && d < hi)
            pd[cursor[d] + (int)(p & 0xffffu)] = make_int2(e, d);
    }
}

static __device__ __forceinline__ uint2 packbf(float4 v) {
    bf16x4_t p = {(bf16_t)v.x, (bf16_t)v.y, (bf16_t)v.z, (bf16_t)v.w};
    union { bf16x4_t b; uint2 u; } c;
    c.b = p;
    return c.u;
}

// prefetch register set: one tile's worth of per-lane data
struct PF {
    float4 xv0, xv1, xv2, xv3;   // x row chunks {2c,2c+1,8+2c,8+2c+1}
    float4 ev0, ev1;             // ea chunks {2c,2c+1}
    int    dstv;                 // dst of edge eb+col
};

static __device__ __forceinline__ void pf_load(PF& p, const int2* __restrict__ pd,
                                               int tile, const float* __restrict__ x,
                                               const float* __restrict__ ea,
                                               int e, int c, int col) {
    const int eb = tile * TW;
    int2 rec = pd[eb + e];
    p.dstv = pd[eb + col].y;
    const float4* xr = (const float4*)(x + (size_t)rec.y * ND);
    const float4* er = (const float4*)(ea + (size_t)rec.x * ED);
    p.xv0 = xr[2 * c]; p.xv1 = xr[2 * c + 1]; p.xv2 = xr[8 + 2 * c]; p.xv3 = xr[8 + 2 * c + 1];
    p.ev0 = er[2 * c]; p.ev1 = er[2 * c + 1];
}

// process one tile held in `cur`; immediately after packing, re-load `cur` with
// pf_tile (if valid) so the loads fly during this tile's GEMM+scatter AND the
// next tile's (other reg set's) processing — prefetch depth 2.
static __device__ __forceinline__ void process_tile(
    PF& cur, int pf_tile, int lim,
    const int2* __restrict__ pd,
    const float* __restrict__ x, const float* __restrict__ ea,
    const bf16_t* __restrict__ w1T, const bf16_t* __restrict__ w2T,
    bf16_t* __restrict__ hS, bf16_t* __restrict__ mT,
    float4 b1v, float4 b2v,
    float* __restrict__ out_sum,
    int lane, int col, int kq, int e, int c)
{
    const float b1r[4] = {b1v.x, b1v.y, b1v.z, b1v.w};
    const float b2r[4] = {b2v.x, b2v.y, b2v.z, b2v.w};
    const int dcur = cur.dstv;

    // pack current tile to bf16 pairs (frees cur for the prefetch overwrite)
    uint2 x0p = packbf(cur.xv0), x1p = packbf(cur.xv1), x2p = packbf(cur.xv2), x3p = packbf(cur.xv3);
    uint2 e0p = packbf(cur.ev0), e1p = packbf(cur.ev1);

    // issue prefetch into cur (depth-2: arrives ~2 tiles later)
    if (pf_tile < lim) pf_load(cur, pd, pf_tile, x, ea, e, c, col);

    // build A-fragments by lane permutation: src lane = col*4 + kq
    const int sl = col * 4 + kq;
    union U8 { u32 u[4]; bf16x8_t v; } a0, a1, a2;
    a0.u[0] = __shfl((int)x0p.x, sl, 64); a0.u[1] = __shfl((int)x0p.y, sl, 64);
    a0.u[2] = __shfl((int)x1p.x, sl, 64); a0.u[3] = __shfl((int)x1p.y, sl, 64);
    a1.u[0] = __shfl((int)x2p.x, sl, 64); a1.u[1] = __shfl((int)x2p.y, sl, 64);
    a1.u[2] = __shfl((int)x3p.x, sl, 64); a1.u[3] = __shfl((int)x3p.y, sl, 64);
    a2.u[0] = __shfl((int)e0p.x, sl, 64); a2.u[1] = __shfl((int)e0p.y, sl, 64);
    a2.u[2] = __shfl((int)e1p.x, sl, 64); a2.u[3] = __shfl((int)e1p.y, sl, 64);

    // GEMM1: h = relu(msg @ W1 + b1)
    f32x4_t acc[4];
    #pragma unroll
    for (int nt = 0; nt < 4; ++nt) {
        const bf16_t* wrow = &w1T[(col + 16 * nt) * W1_LD + kq * 8];
        bf16x8_t f0 = *(const bf16x8_t*)(wrow + 0 * 32);
        bf16x8_t f1 = *(const bf16x8_t*)(wrow + 1 * 32);
        bf16x8_t f2 = *(const bf16x8_t*)(wrow + 2 * 32);
        acc[nt] = (f32x4_t){0.0f, 0.0f, 0.0f, 0.0f};
        acc[nt] = __builtin_amdgcn_mfma_f32_16x16x32_bf16(a0.v, f0, acc[nt], 0, 0, 0);
        acc[nt] = __builtin_amdgcn_mfma_f32_16x16x32_bf16(a1.v, f1, acc[nt], 0, 0, 0);
        acc[nt] = __builtin_amdgcn_mfma_f32_16x16x32_bf16(a2.v, f2, acc[nt], 0, 0, 0);
    }
    #pragma unroll
    for (int nt = 0; nt < 4; ++nt)
        #pragma unroll
        for (int r = 0; r < 4; ++r)
            hS[(4 * kq + r) * H_LD + col + 16 * nt] =
                (bf16_t)fmaxf(acc[nt][r] + b1r[nt], 0.0f);

    // GEMM2: m = relu(h @ W2 + b2)
    const int hb = col * H_LD + kq * 8;
    bf16x8_t ah0 = *(const bf16x8_t*)&hS[hb + 0 * 32];
    bf16x8_t ah1 = *(const bf16x8_t*)&hS[hb + 1 * 32];
    f32x4_t acc2[4];
    #pragma unroll
    for (int nt = 0; nt < 4; ++nt) {
        const bf16_t* wrow = &w2T[(col + 16 * nt) * W2_LD + kq * 8];
        bf16x8_t f0 = *(const bf16x8_t*)(wrow + 0 * 32);
        bf16x8_t f1 = *(const bf16x8_t*)(wrow + 1 * 32);
        acc2[nt] = (f32x4_t){0.0f, 0.0f, 0.0f, 0.0f};
        acc2[nt] = __builtin_amdgcn_mfma_f32_16x16x32_bf16(ah0, f0, acc2[nt], 0, 0, 0);
        acc2[nt] = __builtin_amdgcn_mfma_f32_16x16x32_bf16(ah1, f1, acc2[nt], 0, 0, 0);
    }

    const int dA = __builtin_amdgcn_readlane(dcur, 0);
    const int dB = __builtin_amdgcn_readlane(dcur, 15);
    if (dA == dB) {
        // fast path (~62%): whole tile -> one node
        float s0 = 0.0f, s1 = 0.0f, s2 = 0.0f, s3 = 0.0f;
        #pragma unroll
        for (int r = 0; r < 4; ++r) {
            s0 += fmaxf(acc2[0][r] + b2r[0], 0.0f);
            s1 += fmaxf(acc2[1][r] + b2r[1], 0.0f);
            s2 += fmaxf(acc2[2][r] + b2r[2], 0.0f);
            s3 += fmaxf(acc2[3][r] + b2r[3], 0.0f);
        }
        s0 += __shfl_xor(s0, 16); s0 += __shfl_xor(s0, 32);
        s1 += __shfl_xor(s1, 16); s1 += __shfl_xor(s1, 32);
        s2 += __shfl_xor(s2, 16); s2 += __shfl_xor(s2, 32);
        s3 += __shfl_xor(s3, 16); s3 += __shfl_xor(s3, 32);
        const float sv = (kq == 0) ? s0 : (kq == 1) ? s1 : (kq == 2) ? s2 : s3;
        atomicAdd(&out_sum[(size_t)dA * ND + lane], sv);
    } else {
        // slow path: transposed-m via LDS + fixed 16-iter run-merge
        #pragma unroll
        for (int nt = 0; nt < 4; ++nt)
            #pragma unroll
            for (int r = 0; r < 4; ++r)
                mT[(col + 16 * nt) * MT_LD + 4 * kq + r] =
                    (bf16_t)fmaxf(acc2[nt][r] + b2r[nt], 0.0f);

        bf16x8_t v0 = *(const bf16x8_t*)&mT[lane * MT_LD + 0];
        bf16x8_t v1 = *(const bf16x8_t*)&mT[lane * MT_LD + 8];
        float mval[16];
        #pragma unroll
        for (int j = 0; j < 8; ++j) { mval[j] = (float)v0[j]; mval[8 + j] = (float)v1[j]; }

        int cur2 = dA;
        float s = 0.0f;
        #pragma unroll
        for (int r = 0; r < TW; ++r) {
            const int d = __builtin_amdgcn_readlane(dcur, r);
            if (d != cur2) {
                atomicAdd(&out_sum[(size_t)cur2 * ND + lane], s);
                s = 0.0f; cur2 = d;
            }
            s += mval[r];
        }
        atomicAdd(&out_sum[(size_t)cur2 * ND + lane], s);
    }
}

// ---------------- K4: per-edge MLP via bf16 MFMA — depth-2 prefetch pipeline ----------------
// R25 structure + two prefetch register sets (A/B, loop unrolled x2): load for tile
// t+2*nwx issues when t is packed -> ~1600cy latency cover (vs ~800 at depth 1).
// Weights stay in LDS (R15/R16/R20 law); VGPRs spent on the pipeline instead.
__global__ __launch_bounds__(256, 4)
void edge_mlp_mfma(const float* __restrict__ x,
                   const float* __restrict__ edge_attr,
                   const float* __restrict__ W1, const float* __restrict__ b1,
                   const float* __restrict__ W2, const float* __restrict__ b2,
                   const int2* __restrict__ pd,
                   float* __restrict__ out_sum)
{
    __shared__ __align__(16) bf16_t w1T[HID * W1_LD];        // 13312 B
    __shared__ __align__(16) bf16_t w2T[ND * W2_LD];         //  9216 B
    __shared__ __align__(16) bf16_t sc_all[4 * SC_ELEM];     // 12288 B (total 34816)

    const int t    = threadIdx.x;
    const int lane = t & 63;
    const int w    = t >> 6;         // wave id 0..3
    const int col  = lane & 15;      // MFMA col / A-row selector
    const int kq   = lane >> 4;      // 0..3: k-quarter
    const int e    = lane >> 2;      // gather: edge row 0..15
    const int c    = lane & 3;       // gather: 4 lanes per row

    bf16_t* hS = sc_all + w * SC_ELEM;   // [16][H_LD] (h)
    bf16_t* mT = hS;                      // [64][MT_LD] overlay (m transposed)

    // ---- one-time: transpose W1,W2 into LDS (bf16) ----
    for (int i = t; i < IN_DIM * HID / 4; i += 256) {
        float4 v = ((const float4*)W1)[i];
        int k = i >> 4, j4 = (i & 15) * 4;      // W1[k][j4..j4+3]
        w1T[(j4 + 0) * W1_LD + k] = (bf16_t)v.x;
        w1T[(j4 + 1) * W1_LD + k] = (bf16_t)v.y;
        w1T[(j4 + 2) * W1_LD + k] = (bf16_t)v.z;
        w1T[(j4 + 3) * W1_LD + k] = (bf16_t)v.w;
    }
    for (int i = t; i < HID * ND / 4; i += 256) {
        float4 v = ((const float4*)W2)[i];
        int k = i >> 4, j4 = (i & 15) * 4;
        w2T[(j4 + 0) * W2_LD + k] = (bf16_t)v.x;
        w2T[(j4 + 1) * W2_LD + k] = (bf16_t)v.y;
        w2T[(j4 + 2) * W2_LD + k] = (bf16_t)v.z;
        w2T[(j4 + 3) * W2_LD + k] = (bf16_t)v.w;
    }
    float4 b1v, b2v;
    b1v.x = b1[col]; b1v.y = b1[col + 16]; b1v.z = b1[col + 32]; b1v.w = b1[col + 48];
    b2v.x = b2[col]; b2v.y = b2[col + 16]; b2v.z = b2[col + 32]; b2v.w = b2[col + 48];
    __syncthreads();   // the only block barrier

    // ---- XCD-sliced tile range: slice g = blockIdx&7, contiguous CSR range ----
    const int ntiles = NEDGE / TW;               // 100000
    const int tpx    = ntiles / NXCD;            // 12500 tiles per XCD slice
    const int xg     = blockIdx.x & (NXCD - 1);
    const int bg     = blockIdx.x >> 3;          // 0..127
    const int base   = xg * tpx;
    const int lim    = base + tpx;
    const int wix    = bg * 4 + w;               // wave index within slice (0..511)
    const int nwx    = (gridDim.x >> 3) * 4;     // waves per slice (512)

    // ---- prologue: fill both prefetch sets (wix+nwx < tpx always: 1023 < 12500) ----
    PF A, B;
    pf_load(A, pd, base + wix, x, edge_attr, e, c, col);
    pf_load(B, pd, base + wix + nwx, x, edge_attr, e, c, col);

    for (int tile = base + wix; tile < lim; tile += 2 * nwx) {
        process_tile(A, tile + 2 * nwx, lim, pd, x, edge_attr, w1T, w2T, hS, mT,
                     b1v, b2v, out_sum, lane, col, kq, e, c);
        if (tile + nwx < lim)
            process_tile(B, tile + 3 * nwx, lim, pd, x, edge_attr, w1T, w2T, hS, mT,
                         b1v, b2v, out_sum, lane, col, kq, e, c);
    }
}

// ---------------- K5: finalize out = sum/max(cnt,1) + x ----------------
__global__ void finalize_kernel(const float* __restrict__ x,
                                const int* __restrict__ cnt,
                                float* __restrict__ out)
{
    int i = blockIdx.x * blockDim.x + threadIdx.x;
    int stride = gridDim.x * blockDim.x;
    const int total4 = NODES * ND / 4;
    for (int idx = i; idx < total4; idx += stride) {
        const int n = idx / (ND / 4);
        const float inv = 1.0f / fmaxf((float)cnt[n], 1.0f);
        float4 s = ((const float4*)out)[idx];
        float4 xv = ((const float4*)x)[idx];
        float4 r;
        r.x = s.x * inv + xv.x;
        r.y = s.y * inv + xv.y;
        r.z = s.z * inv + xv.z;
        r.w = s.w * inv + xv.w;
        ((float4*)out)[idx] = r;
    }
}

extern "C" void kernel_launch(void* const* d_in, const int* in_sizes, int n_in,
                              void* d_out, int out_size, void* d_ws, size_t ws_size,
                              hipStream_t stream) {
    const float* x  = (const float*)d_in[0];
    const int*   ei = (const int*)d_in[1];     // int64 in reference -> int32 on device
    const float* ea = (const float*)d_in[2];
    const float* W1 = (const float*)d_in[3];
    const float* b1 = (const float*)d_in[4];
    const float* W2 = (const float*)d_in[5];
    const float* b2 = (const float*)d_in[6];
    float* out = (float*)d_out;

    // d_ws layout (ints): cnt[N] | cursor[N] | pd[2E] | bsum[256] | pk[E]
    int*  cnt    = (int*)d_ws;
    int*  cursor = cnt + NODES;
    int2* pd     = (int2*)(cursor + NODES);
    int*  bsum   = (int*)(pd + NEDGE);
    u32*  pk     = (u32*)(bsum + 256);

    hipLaunchKernelGGL(zero_cnt_kernel, dim3(98), dim3(256), 0, stream, cnt);
    hipLaunchKernelGGL(hist_kernel, dim3(2048), dim3(256), 0, stream, ei, cnt, pk, out);
    hipLaunchKernelGGL(scan_sum_kernel, dim3(SCAN_NBLK), dim3(SCAN_B), 0, stream, cnt, bsum);
    hipLaunchKernelGGL(scan_fill_kernel, dim3(SCAN_NBLK), dim3(SCAN_B), 0, stream, cnt, bsum, cursor);
    hipLaunchKernelGGL(bucket_kernel, dim3(2048), dim3(256), 0, stream, pk, cursor, pd);
    hipLaunchKernelGGL(edge_mlp_mfma, dim3(1024), dim3(256), 0, stream,
                       x, ea, W1, b1, W2, b2, pd, out);
    hipLaunchKernelGGL(finalize_kernel, dim3(1600), dim3(256), 0, stream, x, cnt, out);
}

// Round 27
// 181.254 us; speedup vs baseline: 2.5509x; 2.5509x over previous
//
#include <hip/hip_runtime.h>

// Problem constants (match reference setup_inputs)
#define NODES 50000
#define NEDGE 1600000
#define ND 64      // NODE_DIM
#define ED 32      // EDGE_DIM
#define HID 64     // HIDDEN
#define IN_DIM 96  // ND + ED

#define TW 16        // edges per wave-private micro-tile
#define H_LD   72    // bf16/row: 64+8 pad -> 144 B rows (h tile)
#define MT_LD  24    // mT row stride (bf16): 48 B rows, b128-aligned, low-conflict
#define W1_LD  104   // w1T row stride (bf16)
#define W2_LD  72    // w2T row stride (bf16)
#define SC_ELEM 1536 // per-wave scratch: max(16*H_LD=1152, 64*MT_LD=1536) bf16

typedef __bf16 bf16_t;
typedef __bf16 bf16x4_t __attribute__((ext_vector_type(4)));
typedef __bf16 bf16x8_t __attribute__((ext_vector_type(8)));
typedef float  f32x4_t  __attribute__((ext_vector_type(4)));
typedef unsigned int u32;

#define SCAN_B 256
#define SCAN_NBLK ((NODES + SCAN_B - 1) / SCAN_B)   // 196

#define NXCD 8
#define NODES_PER_G ((NODES + NXCD - 1) / NXCD)   // 6250

// ---------------- K0: zero cnt only (must precede hist's atomics) ----------------
__global__ void zero_cnt_kernel(int* __restrict__ cnt) {
    int i = blockIdx.x * blockDim.x + threadIdx.x;
    int stride = gridDim.x * blockDim.x;
    for (int idx = i; idx < NODES; idx += stride) cnt[idx] = 0;
}

// ---------------- K1: fused out-zero + histogram + packed (dst<<16)|rank ----------------
// out zeroing (12.8MB of float4 stores) overlaps the atomic-latency stalls of the
// histogram loop. Stream order guarantees out is zeroed before edge_mlp_mfma runs.
__global__ void hist_kernel(const int* __restrict__ ei, int* __restrict__ cnt,
                            u32* __restrict__ pk, float* __restrict__ out) {
    int i = blockIdx.x * blockDim.x + threadIdx.x;
    int stride = gridDim.x * blockDim.x;
    {
        float4 z = {0.0f, 0.0f, 0.0f, 0.0f};
        for (int idx = i; idx < NODES * ND / 4; idx += stride) ((float4*)out)[idx] = z;
    }
    for (int e = i; e < NEDGE; e += stride) {
        int d = ei[NEDGE + e];
        int r = atomicAdd(&cnt[d], 1);
        pk[e] = ((u32)d << 16) | (u32)r;
    }
}

// ---------------- K2a: per-block partial sums of cnt ----------------
__global__ void scan_sum_kernel(const int* __restrict__ cnt, int* __restrict__ bsum) {
    __shared__ int sh[SCAN_B];
    const int t = threadIdx.x, b = blockIdx.x;
    const int i = b * SCAN_B + t;
    sh[t] = (i < NODES) ? cnt[i] : 0;
    __syncthreads();
    for (int d = SCAN_B / 2; d > 0; d >>= 1) {
        if (t < d) sh[t] += sh[t + d];
        __syncthreads();
    }
    if (t == 0) bsum[b] = sh[0];
}

// ---------------- K2b: fill cursor (top-scan of bsum computed redundantly per block) ----------------
__global__ void scan_fill_kernel(const int* __restrict__ cnt, const int* __restrict__ bsum,
                                 int* __restrict__ cursor) {
    __shared__ int sh[SCAN_B];
    const int t = threadIdx.x, b = blockIdx.x;
    // phase 1: scan the 196 block sums locally -> this block's base
    sh[t] = (t < SCAN_NBLK) ? bsum[t] : 0;
    __syncthreads();
    for (int d = 1; d < SCAN_B; d <<= 1) {
        int v = (t >= d) ? sh[t - d] : 0;
        __syncthreads();
        sh[t] += v;
        __syncthreads();
    }
    const int base = (b == 0) ? 0 : sh[b - 1];
    __syncthreads();
    // phase 2: scan this block's cnt chunk
    const int i = b * SCAN_B + t;
    int v = (i < NODES) ? cnt[i] : 0;
    sh[t] = v;
    __syncthreads();
    for (int d = 1; d < SCAN_B; d <<= 1) {
        int u = (t >= d) ? sh[t - d] : 0;
        __syncthreads();
        sh[t] += u;
        __syncthreads();
    }
    if (i < NODES) cursor[i] = base + sh[t] - v;   // exclusive
}

// ---------------- K3: bucket-scatter, XCD-partitioned, NO atomics, single stream ----------------
__global__ void bucket_kernel(const u32* __restrict__ pk, const int* __restrict__ cursor,
                              int2* __restrict__ pd) {
    const int g   = blockIdx.x & (NXCD - 1);
    const int bg  = blockIdx.x >> 3;            // block index within group
    const int bpg = gridDim.x >> 3;             // blocks per group
    const int lo  = g * NODES_PER_G;
    const int hi  = min(lo + NODES_PER_G, NODES);
    int i = bg * blockDim.x + threadIdx.x;
    int stride = bpg * blockDim.x;
    for (int e = i; e < NEDGE; e += stride) {
        u32 p = pk[e];
        int d = (int)(p >> 16);
        if (d >= lo && d < hi)
            pd[cursor[d] + (int)(p & 0xffffu)] = make_int2(e, d);
    }
}

static __device__ __forceinline__ uint2 packbf(float4 v) {
    bf16x4_t p = {(bf16_t)v.x, (bf16_t)v.y, (bf16_t)v.z, (bf16_t)v.w};
    union { bf16x4_t b; uint2 u; } c;
    c.b = p;
    return c.u;
}

// ---------------- K4: per-edge MLP via bf16 MFMA — shuffle A-frags, XCD-sliced tiles ----------------
// Blocks with blockIdx&7 == g handle the contiguous CSR tile range of XCD slice g ->
// out-atomics confined to a ~1.6MB dst window per XCD (L2-resident).
// W2 stays in LDS (R15/R16/R20/R26 law: spare VGPRs belong to the depth-1 prefetch
// pipeline; weight hoists and deeper pipelines both spill and collapse L2 reuse).
__global__ __launch_bounds__(256, 4)
void edge_mlp_mfma(const float* __restrict__ x,
                   const float* __restrict__ edge_attr,
                   const float* __restrict__ W1, const float* __restrict__ b1,
                   const float* __restrict__ W2, const float* __restrict__ b2,
                   const int2* __restrict__ pd,
                   float* __restrict__ out_sum)
{
    __shared__ __align__(16) bf16_t w1T[HID * W1_LD];        // 13312 B
    __shared__ __align__(16) bf16_t w2T[ND * W2_LD];         //  9216 B
    __shared__ __align__(16) bf16_t sc_all[4 * SC_ELEM];     // 12288 B (total 34816)

    const int t    = threadIdx.x;
    const int lane = t & 63;
    const int w    = t >> 6;         // wave id 0..3
    const int col  = lane & 15;      // MFMA col / A-row selector
    const int kq   = lane >> 4;      // 0..3: k-quarter
    const int e    = lane >> 2;      // gather: edge row 0..15
    const int c    = lane & 3;       // gather: 4 lanes per row

    bf16_t* hS = sc_all + w * SC_ELEM;   // [16][H_LD] (h)
    bf16_t* mT = hS;                      // [64][MT_LD] overlay (m transposed)

    // ---- one-time: transpose W1,W2 into LDS (bf16) ----
    for (int i = t; i < IN_DIM * HID / 4; i += 256) {
        float4 v = ((const float4*)W1)[i];
        int k = i >> 4, j4 = (i & 15) * 4;      // W1[k][j4..j4+3]
        w1T[(j4 + 0) * W1_LD + k] = (bf16_t)v.x;
        w1T[(j4 + 1) * W1_LD + k] = (bf16_t)v.y;
        w1T[(j4 + 2) * W1_LD + k] = (bf16_t)v.z;
        w1T[(j4 + 3) * W1_LD + k] = (bf16_t)v.w;
    }
    for (int i = t; i < HID * ND / 4; i += 256) {
        float4 v = ((const float4*)W2)[i];
        int k = i >> 4, j4 = (i & 15) * 4;
        w2T[(j4 + 0) * W2_LD + k] = (bf16_t)v.x;
        w2T[(j4 + 1) * W2_LD + k] = (bf16_t)v.y;
        w2T[(j4 + 2) * W2_LD + k] = (bf16_t)v.z;
        w2T[(j4 + 3) * W2_LD + k] = (bf16_t)v.w;
    }
    float b1r[4], b2r[4];
    #pragma unroll
    for (int nt = 0; nt < 4; ++nt) {
        b1r[nt] = b1[col + 16 * nt];
        b2r[nt] = b2[col + 16 * nt];
    }
    __syncthreads();   // the only block barrier

    // ---- XCD-sliced tile range: slice g = blockIdx&7, contiguous CSR range ----
    const int ntiles = NEDGE / TW;               // 100000
    const int tpx    = ntiles / NXCD;            // 12500 tiles per XCD slice
    const int xg     = blockIdx.x & (NXCD - 1);
    const int bg     = blockIdx.x >> 3;          // 0..127
    const int base   = xg * tpx;
    const int lim    = base + tpx;
    const int wix    = bg * 4 + w;               // wave index within slice (0..511)
    const int nwx    = (gridDim.x >> 3) * 4;     // waves per slice (512)

    // ---- prefetch registers: lane (e,c) holds x row chunks {2c,2c+1,8+2c,8+2c+1},
    //      ea chunks {2c,2c+1} (pairs -> shuffle needs no register select) ----
    float4 xv0, xv1, xv2, xv3;
    float4 ev0, ev1;
    int    dstv;                 // dst of edge eb+col (lanes 16..63 replicate)

    { // prologue: load first tile
        const int eb0 = (base + wix) * TW;
        int2 rec = pd[eb0 + e];
        dstv = pd[eb0 + col].y;
        const float4* xr = (const float4*)(x + (size_t)rec.y * ND);
        const float4* er = (const float4*)(edge_attr + (size_t)rec.x * ED);
        xv0 = xr[2 * c]; xv1 = xr[2 * c + 1]; xv2 = xr[8 + 2 * c]; xv3 = xr[8 + 2 * c + 1];
        ev0 = er[2 * c]; ev1 = er[2 * c + 1];
    }

    for (int tile = base + wix; tile < lim; tile += nwx) {
        const int dcur = dstv;   // current tile's dsts (lane i<16 holds dst of row i)

        // ---- pack current tile's data to bf16 pairs (before prefetch overwrite) ----
        uint2 x0p = packbf(xv0), x1p = packbf(xv1), x2p = packbf(xv2), x3p = packbf(xv3);
        uint2 e0p = packbf(ev0), e1p = packbf(ev1);

        // ---- issue next tile's loads (fly during shuffles+GEMM+scatter below) ----
        if (tile + nwx < lim) {
            const int eb1 = (tile + nwx) * TW;
            int2 rec = pd[eb1 + e];
            dstv = pd[eb1 + col].y;
            const float4* xr = (const float4*)(x + (size_t)rec.y * ND);
            const float4* er = (const float4*)(edge_attr + (size_t)rec.x * ED);
            xv0 = xr[2 * c]; xv1 = xr[2 * c + 1]; xv2 = xr[8 + 2 * c]; xv3 = xr[8 + 2 * c + 1];
            ev0 = er[2 * c]; ev1 = er[2 * c + 1];
        }

        // ---- build A-fragments by lane permutation: src lane = col*4 + kq ----
        const int sl = col * 4 + kq;
        union U8 { u32 u[4]; bf16x8_t v; } a0, a1, a2;
        a0.u[0] = __shfl((int)x0p.x, sl, 64); a0.u[1] = __shfl((int)x0p.y, sl, 64);
        a0.u[2] = __shfl((int)x1p.x, sl, 64); a0.u[3] = __shfl((int)x1p.y, sl, 64);
        a1.u[0] = __shfl((int)x2p.x, sl, 64); a1.u[1] = __shfl((int)x2p.y, sl, 64);
        a1.u[2] = __shfl((int)x3p.x, sl, 64); a1.u[3] = __shfl((int)x3p.y, sl, 64);
        a2.u[0] = __shfl((int)e0p.x, sl, 64); a2.u[1] = __shfl((int)e0p.y, sl, 64);
        a2.u[2] = __shfl((int)e1p.x, sl, 64); a2.u[3] = __shfl((int)e1p.y, sl, 64);

        // ---- GEMM1: h[0..15][0..63] = relu(msg @ W1 + b1) ----
        f32x4_t acc[4];
        #pragma unroll
        for (int nt = 0; nt < 4; ++nt) {
            const bf16_t* wrow = &w1T[(col + 16 * nt) * W1_LD + kq * 8];
            bf16x8_t f0 = *(const bf16x8_t*)(wrow + 0 * 32);
            bf16x8_t f1 = *(const bf16x8_t*)(wrow + 1 * 32);
            bf16x8_t f2 = *(const bf16x8_t*)(wrow + 2 * 32);
            acc[nt] = (f32x4_t){0.0f, 0.0f, 0.0f, 0.0f};
            acc[nt] = __builtin_amdgcn_mfma_f32_16x16x32_bf16(a0.v, f0, acc[nt], 0, 0, 0);
            acc[nt] = __builtin_amdgcn_mfma_f32_16x16x32_bf16(a1.v, f1, acc[nt], 0, 0, 0);
            acc[nt] = __builtin_amdgcn_mfma_f32_16x16x32_bf16(a2.v, f2, acc[nt], 0, 0, 0);
        }
        // epilogue: bias+relu -> hS (C/D: row = 4*kq + r, col = col + 16*nt)
        #pragma unroll
        for (int nt = 0; nt < 4; ++nt)
            #pragma unroll
            for (int r = 0; r < 4; ++r)
                hS[(4 * kq + r) * H_LD + col + 16 * nt] =
                    (bf16_t)fmaxf(acc[nt][r] + b1r[nt], 0.0f);

        // ---- GEMM2: m = relu(h @ W2 + b2) ----
        const int hb = col * H_LD + kq * 8;
        bf16x8_t ah0 = *(const bf16x8_t*)&hS[hb + 0 * 32];
        bf16x8_t ah1 = *(const bf16x8_t*)&hS[hb + 1 * 32];
        f32x4_t acc2[4];
        #pragma unroll
        for (int nt = 0; nt < 4; ++nt) {
            const bf16_t* wrow = &w2T[(col + 16 * nt) * W2_LD + kq * 8];
            bf16x8_t f0 = *(const bf16x8_t*)(wrow + 0 * 32);
            bf16x8_t f1 = *(const bf16x8_t*)(wrow + 1 * 32);
            acc2[nt] = (f32x4_t){0.0f, 0.0f, 0.0f, 0.0f};
            acc2[nt] = __builtin_amdgcn_mfma_f32_16x16x32_bf16(ah0, f0, acc2[nt], 0, 0, 0);
            acc2[nt] = __builtin_amdgcn_mfma_f32_16x16x32_bf16(ah1, f1, acc2[nt], 0, 0, 0);
        }

        const int dA = __builtin_amdgcn_readlane(dcur, 0);
        const int dB = __builtin_amdgcn_readlane(dcur, 15);
        if (dA == dB) {
            // ---- fast path (~62%): whole tile -> one node; no mT round-trip ----
            float s0 = 0.0f, s1 = 0.0f, s2 = 0.0f, s3 = 0.0f;
            #pragma unroll
            for (int r = 0; r < 4; ++r) {
                s0 += fmaxf(acc2[0][r] + b2r[0], 0.0f);
                s1 += fmaxf(acc2[1][r] + b2r[1], 0.0f);
                s2 += fmaxf(acc2[2][r] + b2r[2], 0.0f);
                s3 += fmaxf(acc2[3][r] + b2r[3], 0.0f);
            }
            s0 += __shfl_xor(s0, 16); s0 += __shfl_xor(s0, 32);
            s1 += __shfl_xor(s1, 16); s1 += __shfl_xor(s1, 32);
            s2 += __shfl_xor(s2, 16); s2 += __shfl_xor(s2, 32);
            s3 += __shfl_xor(s3, 16); s3 += __shfl_xor(s3, 32);
            const float sv = (kq == 0) ? s0 : (kq == 1) ? s1 : (kq == 2) ? s2 : s3;
            atomicAdd(&out_sum[(size_t)dA * ND + lane], sv);
        } else {
            // ---- slow path: transposed-m via LDS + fixed 16-iter run-merge ----
            #pragma unroll
            for (int nt = 0; nt < 4; ++nt)
                #pragma unroll
                for (int r = 0; r < 4; ++r)
                    mT[(col + 16 * nt) * MT_LD + 4 * kq + r] =
                        (bf16_t)fmaxf(acc2[nt][r] + b2r[nt], 0.0f);

            bf16x8_t v0 = *(const bf16x8_t*)&mT[lane * MT_LD + 0];
            bf16x8_t v1 = *(const bf16x8_t*)&mT[lane * MT_LD + 8];
            float mval[16];
            #pragma unroll
            for (int j = 0; j < 8; ++j) { mval[j] = (float)v0[j]; mval[8 + j] = (float)v1[j]; }

            int cur = dA;
            float s = 0.0f;
            #pragma unroll
            for (int r = 0; r < TW; ++r) {
                const int d = __builtin_amdgcn_readlane(dcur, r);   // SALU, uniform
                if (d != cur) {
                    atomicAdd(&out_sum[(size_t)cur * ND + lane], s);
                    s = 0.0f; cur = d;
                }
                s += mval[r];
            }
            atomicAdd(&out_sum[(size_t)cur * ND + lane], s);
        }
    }
}

// ---------------- K5: finalize out = sum/max(cnt,1) + x ----------------
__global__ void finalize_kernel(const float* __restrict__ x,
                                const int* __restrict__ cnt,
                                float* __restrict__ out)
{
    int i = blockIdx.x * blockDim.x + threadIdx.x;
    int stride = gridDim.x * blockDim.x;
    const int total4 = NODES * ND / 4;
    for (int idx = i; idx < total4; idx += stride) {
        const int n = idx / (ND / 4);
        const float inv = 1.0f / fmaxf((float)cnt[n], 1.0f);
        float4 s = ((const float4*)out)[idx];
        float4 xv = ((const float4*)x)[idx];
        float4 r;
        r.x = s.x * inv + xv.x;
        r.y = s.y * inv + xv.y;
        r.z = s.z * inv + xv.z;
        r.w = s.w * inv + xv.w;
        ((float4*)out)[idx] = r;
    }
}

extern "C" void kernel_launch(void* const* d_in, const int* in_sizes, int n_in,
                              void* d_out, int out_size, void* d_ws, size_t ws_size,
                              hipStream_t stream) {
    const float* x  = (const float*)d_in[0];
    const int*   ei = (const int*)d_in[1];     // int64 in reference -> int32 on device
    const float* ea = (const float*)d_in[2];
    const float* W1 = (const float*)d_in[3];
    const float* b1 = (const float*)d_in[4];
    const float* W2 = (const float*)d_in[5];
    const float* b2 = (const float*)d_in[6];
    float* out = (float*)d_out;

    // d_ws layout (ints): cnt[N] | cursor[N] | pd[2E] | bsum[256] | pk[E]
    int*  cnt    = (int*)d_ws;
    int*  cursor = cnt + NODES;
    int2* pd     = (int2*)(cursor + NODES);
    int*  bsum   = (int*)(pd + NEDGE);
    u32*  pk     = (u32*)(bsum + 256);

    hipLaunchKernelGGL(zero_cnt_kernel, dim3(98), dim3(256), 0, stream, cnt);
    hipLaunchKernelGGL(hist_kernel, dim3(2048), dim3(256), 0, stream, ei, cnt, pk, out);
    hipLaunchKernelGGL(scan_sum_kernel, dim3(SCAN_NBLK), dim3(SCAN_B), 0, stream, cnt, bsum);
    hipLaunchKernelGGL(scan_fill_kernel, dim3(SCAN_NBLK), dim3(SCAN_B), 0, stream, cnt, bsum, cursor);
    hipLaunchKernelGGL(bucket_kernel, dim3(2048), dim3(256), 0, stream, pk, cursor, pd);
    hipLaunchKernelGGL(edge_mlp_mfma, dim3(1024), dim3(256), 0, stream,
                       x, ea, W1, b1, W2, b2, pd, out);
    hipLaunchKernelGGL(finalize_kernel, dim3(1600), dim3(256), 0, stream, x, cnt, out);
}